// Round 5
// baseline (1241.757 us; speedup 1.0000x reference)
//
#include <hip/hip_runtime.h>

// Problem constants (inputs: (32,64,32,32) fp32; embed: (64,1024) fp32)
#define N_PIX  32768   // B*H*W
#define C_DIM  64
#define K_EMB  1024
#define HW     1024    // H*W
#define P_TILE 16      // pixels per block

// d_out layout (float32, concatenated in return order):
//   quantized_out (B,C,H,W) | loss | encoding_indices | perplexity
#define OUT_Q_OFF    0
#define OUT_LOSS_OFF 2097152
#define OUT_IDX_OFF  2097153
#define OUT_PERP_OFF 2129921

// ws layout: counts[1024] @0 | lossAcc @4096

__device__ __forceinline__ unsigned long long pack_score(float d, int k) {
    unsigned int u = __float_as_uint(d);
    u = (u & 0x80000000u) ? ~u : (u | 0x80000000u);  // monotone map, negative-safe
    return ((unsigned long long)u << 32) | (unsigned int)k;
}

__device__ __forceinline__ float bcast_lane(float v, int lane) {
    return __uint_as_float(__builtin_amdgcn_readlane(__float_as_uint(v), lane));
}

// k-major cooperative kernel: 256 threads x 4 k's = all 1024 codes per block;
// 16 pixels per block. The x tile (64c x 16p = 1024 floats) is preloaded into
// 16 VGPRs per lane (lane l, reg r holds x[c=4r+(l>>4)][p=l&15]) and broadcast
// in the hot loop via v_readlane -> SGPR -> v_fmac. NO s_load / ds_read in the
// loop (SMEM is out-of-order -> lgkmcnt(0) full drains killed rounds 2/4; LDS
// has a ds-pipe floor). Only memory op per c: one coalesced e4 load (vmcnt,
// in-order, prefetchable). ||e||^2 fused (ee += e4*e4); ||x||^2 dropped
// (constant under argmin). Accumulators are 16 NAMED float4s (live in AGPRs).
__global__ __launch_bounds__(256, 4) void k_main(
    const float* __restrict__ inp, const float* __restrict__ embed,
    unsigned int* __restrict__ counts, float* __restrict__ lossAcc,
    float* __restrict__ out_q, float* __restrict__ out_idx) {
    __shared__ unsigned long long red[4][P_TILE];
    __shared__ int ksel[P_TILE];

    const int tid = threadIdx.x;
    const int n0  = blockIdx.x * P_TILE;
    const int b   = n0 >> 10;
    const int hw0 = n0 & 1023;
    const float* __restrict__ xu = inp + b * (C_DIM * HW) + hw0;

    // preload x tile into registers: lane l, reg r <- x[c=4r+(l>>4)][p=l&15]
    const int ln_  = tid & 63;
    const int pl   = ln_ & 15;
    const int coff = ln_ >> 4;
    float xr[16];
#pragma unroll
    for (int r = 0; r < 16; ++r)
        xr[r] = xu[(r * 4 + coff) * HW + pl];

    const int k0 = tid * 4;  // this thread's 4 codes (coalesced float4 across wave)

    float4 a0 = {0,0,0,0}, a1 = {0,0,0,0}, a2 = {0,0,0,0}, a3 = {0,0,0,0};
    float4 a4 = {0,0,0,0}, a5 = {0,0,0,0}, a6 = {0,0,0,0}, a7 = {0,0,0,0};
    float4 a8 = {0,0,0,0}, a9 = {0,0,0,0}, a10 = {0,0,0,0}, a11 = {0,0,0,0};
    float4 a12 = {0,0,0,0}, a13 = {0,0,0,0}, a14 = {0,0,0,0}, a15 = {0,0,0,0};
    float4 ee = {0,0,0,0};

#define FMA_P(i) { const float sx = bcast_lane(xr[r], gl + i); \
    a##i.x = fmaf(sx, e4.x, a##i.x); a##i.y = fmaf(sx, e4.y, a##i.y); \
    a##i.z = fmaf(sx, e4.z, a##i.z); a##i.w = fmaf(sx, e4.w, a##i.w); }

#pragma unroll
    for (int r = 0; r < 16; ++r) {          // unrolled: xr[r] needs const index
        for (int g = 0; g < 4; ++g) {       // rolled: keeps code ~7 KB (I$)
            const int c = r * 4 + g;
            const float4 e4 = *reinterpret_cast<const float4*>(embed + c * K_EMB + k0);
            const int gl = g << 4;          // readlane src group
            ee.x = fmaf(e4.x, e4.x, ee.x);
            ee.y = fmaf(e4.y, e4.y, ee.y);
            ee.z = fmaf(e4.z, e4.z, ee.z);
            ee.w = fmaf(e4.w, e4.w, ee.w);
            FMA_P(0)  FMA_P(1)  FMA_P(2)  FMA_P(3)
            FMA_P(4)  FMA_P(5)  FMA_P(6)  FMA_P(7)
            FMA_P(8)  FMA_P(9)  FMA_P(10) FMA_P(11)
            FMA_P(12) FMA_P(13) FMA_P(14) FMA_P(15)
        }
    }
#undef FMA_P

    // per-pixel packed argmin across the block
    const int wv = tid >> 6, ln = tid & 63;
    const float4* accp[P_TILE] = {&a0,&a1,&a2,&a3,&a4,&a5,&a6,&a7,
                                  &a8,&a9,&a10,&a11,&a12,&a13,&a14,&a15};
#pragma unroll
    for (int p = 0; p < P_TILE; ++p) {
        const float4 ac = *accp[p];
        const float s0 = fmaf(-2.f, ac.x, ee.x);
        const float s1 = fmaf(-2.f, ac.y, ee.y);
        const float s2 = fmaf(-2.f, ac.z, ee.z);
        const float s3 = fmaf(-2.f, ac.w, ee.w);
        unsigned long long m = pack_score(s0, k0), t;
        t = pack_score(s1, k0 + 1); if (t < m) m = t;
        t = pack_score(s2, k0 + 2); if (t < m) m = t;
        t = pack_score(s3, k0 + 3); if (t < m) m = t;
        for (int off = 32; off > 0; off >>= 1) {
            unsigned long long o = __shfl_down(m, off, 64);
            if (o < m) m = o;
        }
        if (ln == 0) red[wv][p] = m;
    }
    __syncthreads();
    if (tid < P_TILE) {
        unsigned long long m = red[0][tid];
        if (red[1][tid] < m) m = red[1][tid];
        if (red[2][tid] < m) m = red[2][tid];
        if (red[3][tid] < m) m = red[3][tid];
        const int k = (int)(unsigned int)(m & 0xFFFFFFFFull);
        ksel[tid] = k;
        out_idx[n0 + tid] = (float)k;
        atomicAdd(counts + k, 1u);
    }
    __syncthreads();

    // fused quantize + loss: tid -> (c = tid>>2, 4 pixels); x re-read (cache-hot)
    {
        const int c  = tid >> 2;
        const int pb = (tid & 3) * 4;
        float ls = 0.f;
        float4 qv;
        float* qvp = &qv.x;
        const float4 xv4 = *reinterpret_cast<const float4*>(xu + c * HW + pb);
        const float* xvp = &xv4.x;
#pragma unroll
        for (int j = 0; j < 4; ++j) {
            const int k = ksel[pb + j];
            const float q = embed[c * K_EMB + k];  // gather, L2-resident table
            const float d = q - xvp[j];
            ls = fmaf(d, d, ls);
            qvp[j] = q;
        }
        *reinterpret_cast<float4*>(out_q + b * (C_DIM * HW) + c * HW + hw0 + pb) = qv;
        for (int off = 32; off > 0; off >>= 1) ls += __shfl_down(ls, off, 64);
        if (ln == 0) atomicAdd(lossAcc, ls);
    }
}

__global__ __launch_bounds__(1024) void k_scalar(
    const unsigned int* __restrict__ counts, const float* __restrict__ lossAcc,
    float* __restrict__ out_loss, float* __restrict__ out_perp) {
    __shared__ float red[16];
    const int tid = threadIdx.x;  // 0..1023
    float p = (float)counts[tid] * (1.0f / (float)N_PIX);
    float t = p * logf(p + 1e-10f);   // p==0 -> exactly 0, matches reference
    for (int off = 32; off > 0; off >>= 1) t += __shfl_down(t, off, 64);
    if ((tid & 63) == 0) red[tid >> 6] = t;
    __syncthreads();
    if (tid == 0) {
        float s = 0.f;
#pragma unroll
        for (int i = 0; i < 16; ++i) s += red[i];
        *out_perp = expf(-s);
        *out_loss = 0.25f * (*lossAcc) * (1.0f / (float)(N_PIX * C_DIM));
    }
}

extern "C" void kernel_launch(void* const* d_in, const int* in_sizes, int n_in,
                              void* d_out, int out_size, void* d_ws, size_t ws_size,
                              hipStream_t stream) {
    const float* inp   = (const float*)d_in[0];
    const float* embed = (const float*)d_in[1];
    float* out = (float*)d_out;

    char* ws = (char*)d_ws;
    unsigned int* counts  = (unsigned int*)(ws + 0);
    float*        lossAcc = (float*)(ws + 4096);

    hipMemsetAsync(ws, 0, 4096 + 16, stream);  // counts + lossAcc

    k_main<<<dim3(N_PIX / P_TILE), dim3(256), 0, stream>>>(
        inp, embed, counts, lossAcc, out + OUT_Q_OFF, out + OUT_IDX_OFF);
    k_scalar<<<dim3(1), dim3(1024), 0, stream>>>(counts, lossAcc,
        out + OUT_LOSS_OFF, out + OUT_PERP_OFF);
}

// Round 6
// 197.720 us; speedup vs baseline: 6.2804x; 6.2804x over previous
//
#include <hip/hip_runtime.h>

// Problem constants (inputs: (32,64,32,32) fp32; embed: (64,1024) fp32)
#define N_PIX  32768   // B*H*W
#define C_DIM  64
#define K_EMB  1024
#define HW     1024    // H*W
#define P_TILE 16      // pixels per block

// d_out layout (float32, concatenated in return order):
//   quantized_out (B,C,H,W) | loss | encoding_indices | perplexity
#define OUT_Q_OFF    0
#define OUT_LOSS_OFF 2097152
#define OUT_IDX_OFF  2097153
#define OUT_PERP_OFF 2129921

// ws layout: counts[1024] @0 | lossAcc @4096

__device__ __forceinline__ unsigned long long pack_score(float d, int k) {
    unsigned int u = __float_as_uint(d);
    u = (u & 0x80000000u) ? ~u : (u | 0x80000000u);  // monotone map, negative-safe
    return ((unsigned long long)u << 32) | (unsigned int)k;
}

// k-major cooperative kernel: 256 threads x 4 k's = all 1024 codes per block;
// 16 pixels per block. x tile (4 KB) staged in LDS once; hot loop reads it via
// same-address BROADCAST ds_read_b128 (conflict-free, in-order -> fine-grained
// lgkmcnt, unlike SMEM whose OOO returns force lgkmcnt(0) drains — r4's stall).
// Accumulators are 16 NAMED float4s in straight-line macro code (r4-proven to
// land in AGPRs; NO pointer arrays / readlane — r5's scratch demotion).
// ||e||^2 fused (ee += e4*e4); ||x||^2 dropped (constant under argmin).
__global__ __launch_bounds__(256, 4) void k_main(
    const float* __restrict__ inp, const float* __restrict__ embed,
    unsigned int* __restrict__ counts, float* __restrict__ lossAcc,
    float* __restrict__ out_q, float* __restrict__ out_idx) {
    __shared__ float x_lds[C_DIM * P_TILE];           // 4 KB
    __shared__ unsigned long long red[4][P_TILE];
    __shared__ int ksel[P_TILE];

    const int tid = threadIdx.x;
    const int n0  = blockIdx.x * P_TILE;
    const int b   = n0 >> 10;
    const int hw0 = n0 & 1023;
    const float* __restrict__ xu = inp + b * (C_DIM * HW) + hw0;

    // stage x tile: tid -> (c = tid>>2, 4 pixels), one float4 each
    {
        const int c  = tid >> 2;
        const int p4 = (tid & 3) * 4;
        const float4 v = *reinterpret_cast<const float4*>(xu + c * HW + p4);
        *reinterpret_cast<float4*>(&x_lds[c * P_TILE + p4]) = v;
    }
    __syncthreads();

    const int k0 = tid * 4;  // this thread's 4 codes (coalesced float4 across wave)

    float4 a0 = {0,0,0,0}, a1 = {0,0,0,0}, a2 = {0,0,0,0}, a3 = {0,0,0,0};
    float4 a4 = {0,0,0,0}, a5 = {0,0,0,0}, a6 = {0,0,0,0}, a7 = {0,0,0,0};
    float4 a8 = {0,0,0,0}, a9 = {0,0,0,0}, a10 = {0,0,0,0}, a11 = {0,0,0,0};
    float4 a12 = {0,0,0,0}, a13 = {0,0,0,0}, a14 = {0,0,0,0}, a15 = {0,0,0,0};
    float4 ee = {0,0,0,0};

#define FMA_P(i, xv) \
    a##i.x = fmaf((xv), e4.x, a##i.x); \
    a##i.y = fmaf((xv), e4.y, a##i.y); \
    a##i.z = fmaf((xv), e4.z, a##i.z); \
    a##i.w = fmaf((xv), e4.w, a##i.w);

#pragma unroll 2
    for (int c = 0; c < C_DIM; ++c) {
        const float4 e4 = *reinterpret_cast<const float4*>(embed + c * K_EMB + k0);
        const float4 xq0 = *reinterpret_cast<const float4*>(&x_lds[c * P_TILE + 0]);
        const float4 xq1 = *reinterpret_cast<const float4*>(&x_lds[c * P_TILE + 4]);
        const float4 xq2 = *reinterpret_cast<const float4*>(&x_lds[c * P_TILE + 8]);
        const float4 xq3 = *reinterpret_cast<const float4*>(&x_lds[c * P_TILE + 12]);
        ee.x = fmaf(e4.x, e4.x, ee.x);
        ee.y = fmaf(e4.y, e4.y, ee.y);
        ee.z = fmaf(e4.z, e4.z, ee.z);
        ee.w = fmaf(e4.w, e4.w, ee.w);
        FMA_P(0,  xq0.x) FMA_P(1,  xq0.y) FMA_P(2,  xq0.z) FMA_P(3,  xq0.w)
        FMA_P(4,  xq1.x) FMA_P(5,  xq1.y) FMA_P(6,  xq1.z) FMA_P(7,  xq1.w)
        FMA_P(8,  xq2.x) FMA_P(9,  xq2.y) FMA_P(10, xq2.z) FMA_P(11, xq2.w)
        FMA_P(12, xq3.x) FMA_P(13, xq3.y) FMA_P(14, xq3.z) FMA_P(15, xq3.w)
    }
#undef FMA_P

    // per-pixel packed argmin across the block (macro: no address-taking!)
    const int wv = tid >> 6, ln = tid & 63;
#define RED_P(i) { \
        const float s0 = fmaf(-2.f, a##i.x, ee.x); \
        const float s1 = fmaf(-2.f, a##i.y, ee.y); \
        const float s2 = fmaf(-2.f, a##i.z, ee.z); \
        const float s3 = fmaf(-2.f, a##i.w, ee.w); \
        unsigned long long m = pack_score(s0, k0), t; \
        t = pack_score(s1, k0 + 1); if (t < m) m = t; \
        t = pack_score(s2, k0 + 2); if (t < m) m = t; \
        t = pack_score(s3, k0 + 3); if (t < m) m = t; \
        for (int off = 32; off > 0; off >>= 1) { \
            unsigned long long o = __shfl_down(m, off, 64); \
            if (o < m) m = o; \
        } \
        if (ln == 0) red[wv][i] = m; }
    RED_P(0)  RED_P(1)  RED_P(2)  RED_P(3)
    RED_P(4)  RED_P(5)  RED_P(6)  RED_P(7)
    RED_P(8)  RED_P(9)  RED_P(10) RED_P(11)
    RED_P(12) RED_P(13) RED_P(14) RED_P(15)
#undef RED_P

    __syncthreads();
    if (tid < P_TILE) {
        unsigned long long m = red[0][tid];
        if (red[1][tid] < m) m = red[1][tid];
        if (red[2][tid] < m) m = red[2][tid];
        if (red[3][tid] < m) m = red[3][tid];
        const int k = (int)(unsigned int)(m & 0xFFFFFFFFull);
        ksel[tid] = k;
        out_idx[n0 + tid] = (float)k;
        atomicAdd(counts + k, 1u);
    }
    __syncthreads();

    // fused quantize + loss: tid -> (c = tid>>2, 4 pixels); x from LDS
    {
        const int c  = tid >> 2;
        const int pb = (tid & 3) * 4;
        float ls = 0.f;
        float4 qv;
        float* qvp = &qv.x;
#pragma unroll
        for (int j = 0; j < 4; ++j) {
            const int k = ksel[pb + j];
            const float q  = embed[c * K_EMB + k];  // gather, L2-resident table
            const float xv = x_lds[c * P_TILE + pb + j];
            const float d  = q - xv;
            ls = fmaf(d, d, ls);
            qvp[j] = q;
        }
        *reinterpret_cast<float4*>(out_q + b * (C_DIM * HW) + c * HW + hw0 + pb) = qv;
        for (int off = 32; off > 0; off >>= 1) ls += __shfl_down(ls, off, 64);
        if (ln == 0) atomicAdd(lossAcc, ls);
    }
}

__global__ __launch_bounds__(1024) void k_scalar(
    const unsigned int* __restrict__ counts, const float* __restrict__ lossAcc,
    float* __restrict__ out_loss, float* __restrict__ out_perp) {
    __shared__ float red[16];
    const int tid = threadIdx.x;  // 0..1023
    float p = (float)counts[tid] * (1.0f / (float)N_PIX);
    float t = p * logf(p + 1e-10f);   // p==0 -> exactly 0, matches reference
    for (int off = 32; off > 0; off >>= 1) t += __shfl_down(t, off, 64);
    if ((tid & 63) == 0) red[tid >> 6] = t;
    __syncthreads();
    if (tid == 0) {
        float s = 0.f;
#pragma unroll
        for (int i = 0; i < 16; ++i) s += red[i];
        *out_perp = expf(-s);
        *out_loss = 0.25f * (*lossAcc) * (1.0f / (float)(N_PIX * C_DIM));
    }
}

extern "C" void kernel_launch(void* const* d_in, const int* in_sizes, int n_in,
                              void* d_out, int out_size, void* d_ws, size_t ws_size,
                              hipStream_t stream) {
    const float* inp   = (const float*)d_in[0];
    const float* embed = (const float*)d_in[1];
    float* out = (float*)d_out;

    char* ws = (char*)d_ws;
    unsigned int* counts  = (unsigned int*)(ws + 0);
    float*        lossAcc = (float*)(ws + 4096);

    hipMemsetAsync(ws, 0, 4096 + 16, stream);  // counts + lossAcc

    k_main<<<dim3(N_PIX / P_TILE), dim3(256), 0, stream>>>(
        inp, embed, counts, lossAcc, out + OUT_Q_OFF, out + OUT_IDX_OFF);
    k_scalar<<<dim3(1), dim3(1024), 0, stream>>>(counts, lossAcc,
        out + OUT_LOSS_OFF, out + OUT_PERP_OFF);
}

// Round 7
// 143.588 us; speedup vs baseline: 8.6480x; 1.3770x over previous
//
#include <hip/hip_runtime.h>

// Problem constants (inputs: (32,64,32,32) fp32; embed: (64,1024) fp32)
#define N_PIX  32768   // B*H*W
#define C_DIM  64
#define K_EMB  1024
#define HW     1024    // H*W
#define P_TILE 8       // pixels per block (small so 32 acc floats stay in VGPRs!)

// d_out layout (float32, concatenated in return order):
//   quantized_out (B,C,H,W) | loss | encoding_indices | perplexity
#define OUT_Q_OFF    0
#define OUT_LOSS_OFF 2097152
#define OUT_IDX_OFF  2097153
#define OUT_PERP_OFF 2129921

// ws layout: counts[1024] @0 | lossAcc @4096

__device__ __forceinline__ unsigned long long pack_score(float d, int k) {
    unsigned int u = __float_as_uint(d);
    u = (u & 0x80000000u) ? ~u : (u | 0x80000000u);  // monotone map, negative-safe
    return ((unsigned long long)u << 32) | (unsigned int)k;
}

// k-major cooperative kernel: 256 threads x 4 k's = all 1024 codes per block;
// 8 pixels per block. KEY CHANGE vs r6: only 8 float4 accumulators (32 floats)
// so the register allocator keeps them in VGPRs — r3/r4/r6 all plateaued at
// ~144us with accs demoted to AGPRs (VGPR_Count 44-56), consistent with a ~4x
// effective-rate penalty for VALU FMAs on AGPR operands. Plus a 4-deep rotating
// prefetch of e4 (named regs, ~580cyc x 4 waves of latency cover).
// x tile (2 KB) in LDS, read via same-address broadcast ds_read_b128.
// ||e||^2 fused (ee += e4*e4); ||x||^2 dropped (constant under argmin).
__global__ __launch_bounds__(256, 4) void k_main(
    const float* __restrict__ inp, const float* __restrict__ embed,
    unsigned int* __restrict__ counts, float* __restrict__ lossAcc,
    float* __restrict__ out_q, float* __restrict__ out_idx) {
    __shared__ float x_lds[C_DIM * P_TILE];           // 2 KB
    __shared__ unsigned long long red[4][P_TILE];
    __shared__ int ksel[P_TILE];
    __shared__ float lred[2];

    const int tid = threadIdx.x;
    const int n0  = blockIdx.x * P_TILE;
    const int b   = n0 >> 10;
    const int hw0 = n0 & 1023;
    const float* __restrict__ xu = inp + b * (C_DIM * HW) + hw0;

    // stage x tile: first 128 threads -> (c = tid>>1, one float4 half-row)
    if (tid < 128) {
        const int c  = tid >> 1;
        const int p4 = (tid & 1) * 4;
        *reinterpret_cast<float4*>(&x_lds[c * P_TILE + p4]) =
            *reinterpret_cast<const float4*>(xu + c * HW + p4);
    }
    __syncthreads();

    const int k0 = tid * 4;  // this thread's 4 codes (coalesced float4 across wave)
    const float4* __restrict__ eb =
        reinterpret_cast<const float4*>(embed) + (k0 >> 2);  // row stride 256 float4

    float4 a0 = {0,0,0,0}, a1 = {0,0,0,0}, a2 = {0,0,0,0}, a3 = {0,0,0,0};
    float4 a4 = {0,0,0,0}, a5 = {0,0,0,0}, a6 = {0,0,0,0}, a7 = {0,0,0,0};
    float4 ee = {0,0,0,0};

#define FMA_P(i, xv, E) \
    a##i.x = fmaf((xv), E.x, a##i.x); \
    a##i.y = fmaf((xv), E.y, a##i.y); \
    a##i.z = fmaf((xv), E.z, a##i.z); \
    a##i.w = fmaf((xv), E.w, a##i.w);

#define BODY(E, c) { \
    const float4 xq0 = *reinterpret_cast<const float4*>(&x_lds[(c) * P_TILE + 0]); \
    const float4 xq1 = *reinterpret_cast<const float4*>(&x_lds[(c) * P_TILE + 4]); \
    ee.x = fmaf(E.x, E.x, ee.x); ee.y = fmaf(E.y, E.y, ee.y); \
    ee.z = fmaf(E.z, E.z, ee.z); ee.w = fmaf(E.w, E.w, ee.w); \
    FMA_P(0, xq0.x, E) FMA_P(1, xq0.y, E) FMA_P(2, xq0.z, E) FMA_P(3, xq0.w, E) \
    FMA_P(4, xq1.x, E) FMA_P(5, xq1.y, E) FMA_P(6, xq1.z, E) FMA_P(7, xq1.w, E) }

    // 4-deep rotating prefetch: N-loads for c+4..c+7 issued before consuming E
    float4 E0 = eb[0 * 256], E1 = eb[1 * 256], E2 = eb[2 * 256], E3 = eb[3 * 256];
#pragma unroll 1
    for (int c = 0; c < C_DIM; c += 4) {
        const int cn = (c + 4 < C_DIM) ? (c + 4) : c;  // tail: harmless re-read
        float4 N0 = eb[(cn + 0) * 256];
        float4 N1 = eb[(cn + 1) * 256];
        float4 N2 = eb[(cn + 2) * 256];
        float4 N3 = eb[(cn + 3) * 256];
        BODY(E0, c + 0)
        BODY(E1, c + 1)
        BODY(E2, c + 2)
        BODY(E3, c + 3)
        E0 = N0; E1 = N1; E2 = N2; E3 = N3;
    }
#undef BODY
#undef FMA_P

    // per-pixel packed argmin across the block (macro: no address-taking!)
    const int wv = tid >> 6, ln = tid & 63;
#define RED_P(i) { \
        const float s0 = fmaf(-2.f, a##i.x, ee.x); \
        const float s1 = fmaf(-2.f, a##i.y, ee.y); \
        const float s2 = fmaf(-2.f, a##i.z, ee.z); \
        const float s3 = fmaf(-2.f, a##i.w, ee.w); \
        unsigned long long m = pack_score(s0, k0), t; \
        t = pack_score(s1, k0 + 1); if (t < m) m = t; \
        t = pack_score(s2, k0 + 2); if (t < m) m = t; \
        t = pack_score(s3, k0 + 3); if (t < m) m = t; \
        for (int off = 32; off > 0; off >>= 1) { \
            unsigned long long o = __shfl_down(m, off, 64); \
            if (o < m) m = o; \
        } \
        if (ln == 0) red[wv][i] = m; }
    RED_P(0) RED_P(1) RED_P(2) RED_P(3)
    RED_P(4) RED_P(5) RED_P(6) RED_P(7)
#undef RED_P

    __syncthreads();
    if (tid < P_TILE) {
        unsigned long long m = red[0][tid];
        if (red[1][tid] < m) m = red[1][tid];
        if (red[2][tid] < m) m = red[2][tid];
        if (red[3][tid] < m) m = red[3][tid];
        const int k = (int)(unsigned int)(m & 0xFFFFFFFFull);
        ksel[tid] = k;
        out_idx[n0 + tid] = (float)k;
        atomicAdd(counts + k, 1u);
    }
    __syncthreads();

    // fused quantize + loss: first 128 threads -> (c = tid>>1, 4 pixels)
    if (tid < 128) {
        const int c  = tid >> 1;
        const int pb = (tid & 1) * 4;
        float ls = 0.f;
        float4 qv;
        float* qvp = &qv.x;
#pragma unroll
        for (int j = 0; j < 4; ++j) {
            const int k = ksel[pb + j];
            const float q  = embed[c * K_EMB + k];  // gather, L2-resident table
            const float xv = x_lds[c * P_TILE + pb + j];
            const float d  = q - xv;
            ls = fmaf(d, d, ls);
            qvp[j] = q;
        }
        *reinterpret_cast<float4*>(out_q + b * (C_DIM * HW) + c * HW + hw0 + pb) = qv;
        for (int off = 32; off > 0; off >>= 1) ls += __shfl_down(ls, off, 64);
        if (ln == 0) lred[wv] = ls;   // only waves 0,1 reach here
    }
    __syncthreads();
    if (tid == 0) atomicAdd(lossAcc, lred[0] + lred[1]);  // 1 atomic per block
}

__global__ __launch_bounds__(1024) void k_scalar(
    const unsigned int* __restrict__ counts, const float* __restrict__ lossAcc,
    float* __restrict__ out_loss, float* __restrict__ out_perp) {
    __shared__ float red[16];
    const int tid = threadIdx.x;  // 0..1023
    float p = (float)counts[tid] * (1.0f / (float)N_PIX);
    float t = p * logf(p + 1e-10f);   // p==0 -> exactly 0, matches reference
    for (int off = 32; off > 0; off >>= 1) t += __shfl_down(t, off, 64);
    if ((tid & 63) == 0) red[tid >> 6] = t;
    __syncthreads();
    if (tid == 0) {
        float s = 0.f;
#pragma unroll
        for (int i = 0; i < 16; ++i) s += red[i];
        *out_perp = expf(-s);
        *out_loss = 0.25f * (*lossAcc) * (1.0f / (float)(N_PIX * C_DIM));
    }
}

extern "C" void kernel_launch(void* const* d_in, const int* in_sizes, int n_in,
                              void* d_out, int out_size, void* d_ws, size_t ws_size,
                              hipStream_t stream) {
    const float* inp   = (const float*)d_in[0];
    const float* embed = (const float*)d_in[1];
    float* out = (float*)d_out;

    char* ws = (char*)d_ws;
    unsigned int* counts  = (unsigned int*)(ws + 0);
    float*        lossAcc = (float*)(ws + 4096);

    hipMemsetAsync(ws, 0, 4096 + 16, stream);  // counts + lossAcc

    k_main<<<dim3(N_PIX / P_TILE), dim3(256), 0, stream>>>(
        inp, embed, counts, lossAcc, out + OUT_Q_OFF, out + OUT_IDX_OFF);
    k_scalar<<<dim3(1), dim3(1024), 0, stream>>>(counts, lossAcc,
        out + OUT_LOSS_OFF, out + OUT_PERP_OFF);
}